// Round 3
// baseline (365.159 us; speedup 1.0000x reference)
//
#include <hip/hip_runtime.h>
#include <hip/hip_bf16.h>
#include <math.h>

// x(32,512,768) fp32 -> LayerNorm(768) -> Linear 768x3072 + bias -> exact GELU
// M = 16384, K = 768, N = 3072. Output fp32.
#define M_ROWS 16384
#define K_DIM  768
#define N_DIM  3072
#define NKT    (K_DIM / 64)

typedef __bf16 bf16x8 __attribute__((ext_vector_type(8)));
typedef float  f32x4  __attribute__((ext_vector_type(4)));
typedef unsigned short u16x4 __attribute__((ext_vector_type(4)));

__device__ __forceinline__ unsigned short f2bf(float f) {
    unsigned int u = __float_as_uint(f);
    unsigned int r = (u + 0x7fffu + ((u >> 16) & 1u)) >> 16;   // RNE
    return (unsigned short)r;
}

__device__ __forceinline__ void async16(const unsigned short* g, unsigned short* l) {
    __builtin_amdgcn_global_load_lds(
        (const __attribute__((address_space(1))) unsigned int*)g,
        (__attribute__((address_space(3))) unsigned int*)l,
        16, 0, 0);
}

// tanh-form GELU; max |err| vs erf ~1e-3 (absmax budget 0.112, bf16 path uses 0.031)
__device__ __forceinline__ float gelu_fast(float h) {
    float h2 = h * h;
    float z2 = h * __builtin_fmaf(0.0713548162f, h2, 1.5957691216f); // 2*z
    float E  = __expf(z2);
    float r  = __builtin_amdgcn_rcpf(1.0f + E);
    return h - h * r;
}

// ---------- 1) LayerNorm + cast to bf16 ----------
__global__ __launch_bounds__(256) void ln_kernel(const float* __restrict__ x,
                                                 const float* __restrict__ gamma,
                                                 const float* __restrict__ beta,
                                                 unsigned short* __restrict__ xn) {
    int wave = threadIdx.x >> 6;
    int lane = threadIdx.x & 63;
    int row  = blockIdx.x * 4 + wave;
    const f32x4* xr = (const f32x4*)(x + (size_t)row * K_DIM);
    const f32x4* g4 = (const f32x4*)gamma;
    const f32x4* b4 = (const f32x4*)beta;

    f32x4 v[3];
    float s = 0.f, ss = 0.f;
#pragma unroll
    for (int q = 0; q < 3; q++) {
        v[q] = xr[lane + 64 * q];
#pragma unroll
        for (int e = 0; e < 4; e++) { s += v[q][e]; ss += v[q][e] * v[q][e]; }
    }
#pragma unroll
    for (int off = 32; off; off >>= 1) {
        s  += __shfl_xor(s,  off, 64);
        ss += __shfl_xor(ss, off, 64);
    }
    float mu   = s * (1.f / K_DIM);
    float var  = ss * (1.f / K_DIM) - mu * mu;
    float rstd = rsqrtf(var + 1e-12f);

    u16x4* xo = (u16x4*)(xn + (size_t)row * K_DIM);
#pragma unroll
    for (int q = 0; q < 3; q++) {
        f32x4 gv = g4[lane + 64 * q];
        f32x4 bv = b4[lane + 64 * q];
        u16x4 o;
#pragma unroll
        for (int e = 0; e < 4; e++)
            o[e] = f2bf((v[q][e] - mu) * rstd * gv[e] + bv[e]);
        xo[lane + 64 * q] = o;
    }
}

// ---------- 2) W [K,N] fp32 -> Wt [N,K] bf16 ----------
__global__ __launch_bounds__(256) void wcast_kernel(const float* __restrict__ W,
                                                    unsigned short* __restrict__ wt) {
    __shared__ float tile[32][33];
    int bx = blockIdx.x, by = blockIdx.y;
    int tx = threadIdx.x, ty = threadIdx.y;
#pragma unroll
    for (int r = 0; r < 4; r++)
        tile[ty + 8 * r][tx] = W[(size_t)(by * 32 + ty + 8 * r) * N_DIM + bx * 32 + tx];
    __syncthreads();
#pragma unroll
    for (int r = 0; r < 4; r++)
        wt[(size_t)(bx * 32 + ty + 8 * r) * K_DIM + by * 32 + tx] = f2bf(tile[tx][ty + 8 * r]);
}

// ---------- 3) GEMM + bias + GELU ----------
// 128x128 tile, BK=64, 4 waves (2x2), wave 64x64 via 4x4 MFMA 16x16x32 bf16.
// DOUBLE-BUFFERED K-loop, one barrier per kt: loads for kt+1 are issued right
// after the barrier that publishes kt, so the barrier's vmcnt(0) drain waits on
// loads that had a full compute phase in flight (latency hidden).
// LDS chunk-XOR swizzle (chunk' = chunk ^ (row&7)) on the global source side
// keeps ds_read_b128 conflict-free (verified: SQ_LDS_BANK_CONFLICT == 0).
__global__ __launch_bounds__(256) void gemm_kernel(const unsigned short* __restrict__ A,
                                                   const unsigned short* __restrict__ B,
                                                   const float* __restrict__ bias,
                                                   float* __restrict__ C) {
    __shared__ __attribute__((aligned(16))) unsigned short As[2][128 * 64];
    __shared__ __attribute__((aligned(16))) unsigned short Bs[2][128 * 64];

    int tid  = threadIdx.x;
    int lane = tid & 63;
    int wid  = tid >> 6;
    int waveM = wid >> 1;
    int waveN = wid & 1;
    int bm = blockIdx.y;
    int bn = blockIdx.x;

    f32x4 acc[4][4] = {};   // acc[i][j]: i -> N sub-tile (W as A-operand), j -> M sub-tile

    // staging: row = tid>>3 (+32*i), phys chunk = tid&7, source chunk swizzled
    int srow   = tid >> 3;
    int schunk = (tid & 7) ^ (srow & 7);
    const unsigned short* Ag = A + (size_t)(bm * 128 + srow) * K_DIM + schunk * 8;
    const unsigned short* Bg = B + (size_t)(bn * 128 + srow) * K_DIM + schunk * 8;

    int mrow = lane & 15;
    int quad = lane >> 4;
    int swz  = mrow & 7;

    // prologue: stage kt=0 into buffer 0
#pragma unroll
    for (int i = 0; i < 4; i++) {
        async16(Ag + (size_t)i * 32 * K_DIM, &As[0][tid * 8 + i * 2048]);
        async16(Bg + (size_t)i * 32 * K_DIM, &Bs[0][tid * 8 + i * 2048]);
    }

    for (int kt = 0; kt < NKT; ++kt) {
        int cur = kt & 1;
        __syncthreads();          // publishes buf[cur]; drains this wave's loads

        if (kt + 1 < NKT) {       // prefetch kt+1 into the other buffer
            int nxt = cur ^ 1;
#pragma unroll
            for (int i = 0; i < 4; i++) {
                async16(Ag + (size_t)i * 32 * K_DIM + (kt + 1) * 64, &As[nxt][tid * 8 + i * 2048]);
                async16(Bg + (size_t)i * 32 * K_DIM + (kt + 1) * 64, &Bs[nxt][tid * 8 + i * 2048]);
            }
        }

#pragma unroll
        for (int s = 0; s < 2; s++) {
            int chunk = ((s * 4 + quad) ^ swz) * 8;
            bf16x8 wf[4], xf[4];
#pragma unroll
            for (int i = 0; i < 4; i++)
                wf[i] = *(const bf16x8*)(&Bs[cur][(waveN * 64 + i * 16 + mrow) * 64 + chunk]);
#pragma unroll
            for (int j = 0; j < 4; j++)
                xf[j] = *(const bf16x8*)(&As[cur][(waveM * 64 + j * 16 + mrow) * 64 + chunk]);
#pragma unroll
            for (int i = 0; i < 4; i++)
#pragma unroll
                for (int j = 0; j < 4; j++)
                    acc[i][j] = __builtin_amdgcn_mfma_f32_16x16x32_bf16(wf[i], xf[j], acc[i][j], 0, 0, 0);
        }
    }

    // D layout: lane&15 -> B-operand row (m), quad*4+reg -> A-operand row (n)
    int m0 = bm * 128 + waveM * 64 + mrow;
    int n0 = bn * 128 + waveN * 64 + quad * 4;
#pragma unroll
    for (int i = 0; i < 4; i++) {
        f32x4 bb = *(const f32x4*)(bias + n0 + i * 16);
#pragma unroll
        for (int j = 0; j < 4; j++) {
            f32x4 o;
#pragma unroll
            for (int r = 0; r < 4; r++)
                o[r] = gelu_fast(acc[i][j][r] + bb[r]);
            *(f32x4*)(C + (size_t)(m0 + j * 16) * N_DIM + n0 + i * 16) = o;
        }
    }
}

extern "C" void kernel_launch(void* const* d_in, const int* in_sizes, int n_in,
                              void* d_out, int out_size, void* d_ws, size_t ws_size,
                              hipStream_t stream) {
    const float* x     = (const float*)d_in[0];
    const float* gamma = (const float*)d_in[1];
    const float* beta  = (const float*)d_in[2];
    const float* W     = (const float*)d_in[3];
    const float* bias  = (const float*)d_in[4];
    float* out = (float*)d_out;

    unsigned short* xn = (unsigned short*)d_ws;
    unsigned short* wt = xn + (size_t)M_ROWS * K_DIM;

    ln_kernel<<<M_ROWS / 4, 256, 0, stream>>>(x, gamma, beta, xn);
    wcast_kernel<<<dim3(N_DIM / 32, K_DIM / 32), dim3(32, 8), 0, stream>>>(W, wt);
    gemm_kernel<<<dim3(N_DIM / 128, M_ROWS / 128), 256, 0, stream>>>(xn, wt, bias, out);
}